// Round 8
// baseline (482.981 us; speedup 1.0000x reference)
//
#include <hip/hip_runtime.h>

// Flash attention forward, fp32 in/out, fp16 MFMA compute.
// B=8, SQ=SK=4096, D=64. scores = (Q/x5) K^T ; softmax ; O = P V.
// R22 = R16 + KSPLIT=8 occupancy (R20's C-bias REVERTED: it regressed 61->66
// by putting a loop-carried -m_i init at the head of the QK MFMA cluster).
// Evidence: R16/R20 VALU deletions barely moved time -> not issue-bound;
// wall/demand ~ 4x -> dependency-stall-bound at 2 waves/SIMD. Fix: more
// resident waves, zero per-wave cost: KSPLIT 4->8 (grid 1024 = 4 blocks/CU
// at launch_bounds (256,4); VGPR already exactly 128 = the cap). Per-wave
// structure byte-identical to R16 (MT=2, 16 b128/kt, fused-l ones-MFMA,
// permlane cross-half max, setprio MFMA clusters, defer-max THR=11.5,
// normalized Ap, dbuf global_load_lds, XCD-affine flat grid: 8 splits x
// 16 q-blocks of one K/V stream share an XCD). Costs: Q/Ap/combine traffic
// x2 (~+34MB HBM), ws 25.8->43.6 MB.

typedef _Float16 f16x8 __attribute__((ext_vector_type(8)));
typedef _Float16 f16x4 __attribute__((ext_vector_type(4)));
typedef __fp16   h16x2 __attribute__((ext_vector_type(2)));
typedef float    f32x4 __attribute__((ext_vector_type(4)));
typedef float    f32x16 __attribute__((ext_vector_type(16)));

constexpr int kB  = 8;
constexpr int kSQ = 4096;
constexpr int kSK = 4096;
constexpr int kD  = 64;
constexpr int KSPLIT = 8;
constexpr int SKH = kSK / KSPLIT;     // 512 keys per split
constexpr int BQ  = 256;              // 4 waves x 2 M-tiles x 32 Q rows
constexpr int MT  = 2;
constexpr int BK  = 64;
constexpr size_t APART = (size_t)kB * kSQ * kD;
constexpr float kLog2e = 1.44269504088896340736f;
constexpr float kDeferThr = 11.5f;    // exp2-domain (~8 nats); P <= 2^11.5

static __device__ __forceinline__ f16x4 pack4(float a, float b, float c, float d) {
    h16x2 p0 = __builtin_amdgcn_cvt_pkrtz(a, b);
    h16x2 p1 = __builtin_amdgcn_cvt_pkrtz(c, d);
    f16x4 r;
    r[0] = (_Float16)p0[0]; r[1] = (_Float16)p0[1];
    r[2] = (_Float16)p1[0]; r[3] = (_Float16)p1[1];
    return r;
}
static __device__ __forceinline__ f16x8 pack8(const float4& a, const float4& c) {
    f16x4 lo = pack4(a.x, a.y, a.z, a.w);
    f16x4 hi = pack4(c.x, c.y, c.z, c.w);
    f16x8 f;
    f[0] = lo[0]; f[1] = lo[1]; f[2] = lo[2]; f[3] = lo[3];
    f[4] = hi[0]; f[5] = hi[1]; f[6] = hi[2]; f[7] = hi[3];
    return f;
}
static __device__ __forceinline__ unsigned pkrtz_u(float a, float b) {
    union { h16x2 h; unsigned u; } cv;
    cv.h = __builtin_amdgcn_cvt_pkrtz(a, b);
    return cv.u;
}
static __device__ __forceinline__ float xhalf_max(float x) {
    // max(x[lane], x[lane^32]) in every lane, VALU-only.
    union { float f; unsigned u; } uv; uv.f = x;
    auto pr = __builtin_amdgcn_permlane32_swap(uv.u, uv.u, false, false);
    union { unsigned u; float f; } r0, r1;
    r0.u = pr[0]; r1.u = pr[1];
    return fmaxf(r0.f, r1.f);
}

typedef const __attribute__((address_space(1))) unsigned int* gu32p;
typedef __attribute__((address_space(3))) unsigned int* lu32p;
static __device__ __forceinline__ void gload_lds16(const void* g, void* l) {
    __builtin_amdgcn_global_load_lds((gu32p)g, (lu32p)l, 16, 0, 0);
}

// P slice (8 regs of one 32-key C-block) -> f16x8 PV fragment.
// C/D rows: key = (r&3)+8*(r>>2)+4*hi. Pair cvtpk(p[2i],p[2i+1]) with
// cvtpk(p[2i+4],p[2i+5]); one permlane32_swap fills two output words.
#define PA_SLICE(dst, sv, rb) do {                                          \
    unsigned c0 = pkrtz_u((sv)[(rb)+0], (sv)[(rb)+1]);                      \
    unsigned c1 = pkrtz_u((sv)[(rb)+2], (sv)[(rb)+3]);                      \
    unsigned c2 = pkrtz_u((sv)[(rb)+4], (sv)[(rb)+5]);                      \
    unsigned c3 = pkrtz_u((sv)[(rb)+6], (sv)[(rb)+7]);                      \
    auto r02 = __builtin_amdgcn_permlane32_swap(c0, c2, false, false);      \
    auto r13 = __builtin_amdgcn_permlane32_swap(c1, c3, false, false);      \
    union { unsigned u[4]; f16x8 v; } _r;                                   \
    _r.u[0] = r02[0]; _r.u[1] = r13[0]; _r.u[2] = r02[1]; _r.u[3] = r13[1]; \
    dst = _r.v;                                                             \
} while (0)

// ---------------- pre-pass: K -> Kh (swizzled fp16), V -> Vt (transposed,
// tiled, swizzled fp16). Kh[b][k][blk fb^(k&7)][8]; Vt[b][kt][f][blk kb^(f&7)][8].
__global__ __launch_bounds__(256, 2)
void fattn_prepass(const float* __restrict__ Kg,
                   const float* __restrict__ Vg,
                   _Float16* __restrict__ Kh,
                   _Float16* __restrict__ Vt)
{
    __shared__ _Float16 tr[kD][BK];

    const int tid = threadIdx.x;
    const int kt  = blockIdx.x;
    const int b   = blockIdx.y;

    const int k = tid >> 2;
    const int p = tid & 3;
    const int gk = kt * BK + k;

    {
        const float* src = Kg + ((size_t)b * kSK + gk) * kD + p * 16;
        const float4 a0 = *(const float4*)(src + 0);
        const float4 a1 = *(const float4*)(src + 4);
        const float4 a2 = *(const float4*)(src + 8);
        const float4 a3 = *(const float4*)(src + 12);
        _Float16* dst = Kh + ((size_t)b * kSK + gk) * kD;
        const int fb0 = 2 * p, fb1 = 2 * p + 1;
        *(f16x8*)&dst[(fb0 ^ (gk & 7)) * 8] = pack8(a0, a1);
        *(f16x8*)&dst[(fb1 ^ (gk & 7)) * 8] = pack8(a2, a3);
    }
    {
        const float* src = Vg + ((size_t)b * kSK + gk) * kD + p * 16;
        const float4 a0 = *(const float4*)(src + 0);
        const float4 a1 = *(const float4*)(src + 4);
        const float4 a2 = *(const float4*)(src + 8);
        const float4 a3 = *(const float4*)(src + 12);
        const float v[16] = {a0.x,a0.y,a0.z,a0.w, a1.x,a1.y,a1.z,a1.w,
                             a2.x,a2.y,a2.z,a2.w, a3.x,a3.y,a3.z,a3.w};
#pragma unroll
        for (int j = 0; j < 16; ++j)
            tr[p * 16 + j][k] = (_Float16)v[j];
    }
    __syncthreads();
    {
        const int f  = tid >> 2;
        const int p2 = tid & 3;
        const f16x8 b0 = *(const f16x8*)&tr[f][p2 * 16 + 0];
        const f16x8 b1 = *(const f16x8*)&tr[f][p2 * 16 + 8];
        _Float16* dst = Vt + (((size_t)b * 64 + kt) * kD + f) * BK;
        const int kb0 = 2 * p2, kb1 = 2 * p2 + 1;
        *(f16x8*)&dst[(kb0 ^ (f & 7)) * 8] = b0;
        *(f16x8*)&dst[(kb1 ^ (f & 7)) * 8] = b1;
    }
}

// ---------------- main partial kernel (32x32x16 MFMA, MT=2, phase-split) ----------------
__global__ __launch_bounds__(256, 4)
void fattn_partial(const float* __restrict__ Qg,
                   const _Float16* __restrict__ Kh,
                   const _Float16* __restrict__ Vt,
                   const float* __restrict__ sdiv,
                   _Float16* __restrict__ Ap,   // [KSPLIT][B][SQ][D] NORMALIZED (O/l)
                   float2* __restrict__ MLp)    // [KSPLIT][B][SQ] (m,l) exp2-domain
{
    __shared__ __align__(16) _Float16 sK[2][BK * kD];   // 16 KB
    __shared__ __align__(16) _Float16 sV[2][kD * BK];   // 16 KB

    const int tid  = threadIdx.x;
    const int w    = tid >> 6;
    const int lane = tid & 63;
    const int l31  = lane & 31;
    const int hi   = lane >> 5;

    // XCD-affine decode: flat = c + 64*qi; c = (b,ks); all 16 q-blocks of one
    // K/V stream share an XCD (flat%8 invariant across qi).
    const int flat = blockIdx.x;
    const int c    = flat & 63;
    const int qi   = flat >> 6;
    const int b    = c >> 3;      // KSPLIT = 8
    const int ks   = c & 7;
    const int qb   = qi * BQ;

    const float qscale = kLog2e / sdiv[0];   // exp2 domain

    const float* Qb = Qg + ((size_t)b * kSQ + qb) * kD;
    const _Float16* Khb = Kh + ((size_t)b * kSK + (size_t)ks * SKH) * kD;
    const _Float16* Vtb = Vt + (((size_t)b * 64 + (size_t)ks * (SKH / BK)) * kD) * BK;

    // ---- Q fragments: qf[mt][ds][j] = Q[q][ds*16 + hi*8 + j]*qscale,
    //      q = qb + w*64 + mt*32 + l31 (lane-col of all MFMAs) ----
    f16x8 qf[MT][4];
#pragma unroll
    for (int mt = 0; mt < MT; ++mt) {
        const float* qrow = Qb + (size_t)(w * 64 + mt * 32 + l31) * kD;
#pragma unroll
        for (int ds = 0; ds < 4; ++ds) {
            const float4 a  = *(const float4*)(qrow + ds * 16 + hi * 8);
            const float4 cc = *(const float4*)(qrow + ds * 16 + hi * 8 + 4);
            float4 as = make_float4(a.x * qscale, a.y * qscale, a.z * qscale, a.w * qscale);
            float4 cs = make_float4(cc.x * qscale, cc.y * qscale, cc.z * qscale, cc.w * qscale);
            qf[mt][ds] = pack8(as, cs);
        }
    }

    // ones A-fragment for the fused-l MFMA
    f16x8 ones;
#pragma unroll
    for (int j = 0; j < 8; ++j) ones[j] = (_Float16)1.0f;

    // Swizzled LDS fragment offsets (halves); identical pattern for K and V:
    // row = l31 (+32 for second block), 16B slot = (2*i + hi) ^ (row & 7).
    int offA[4];
#pragma unroll
    for (int i = 0; i < 4; ++i)
        offA[i] = l31 * 64 + (((2 * i + hi) ^ (l31 & 7)) * 8);

    // ---- async staging: 4 global_load_lds per wave ----
    auto stage = [&](int kt, int buf) {
        const char* gk = (const char*)(Khb + (size_t)kt * BK * kD) + w * 2048 + lane * 16;
        const char* gv = (const char*)(Vtb + (size_t)kt * kD * BK) + w * 2048 + lane * 16;
        char* lk = (char*)&sK[buf][0] + w * 2048;
        char* lv = (char*)&sV[buf][0] + w * 2048;
        gload_lds16(gk,        lk);
        gload_lds16(gk + 1024, lk + 1024);
        gload_lds16(gv,        lv);
        gload_lds16(gv + 1024, lv + 1024);
    };

    f32x16 oL[MT], oH[MT];         // O^T accumulators: d rows 0-31 / 32-63
    f32x16 ol[MT];                 // fused-l accumulator (only [0] consumed)
    float m_i[MT];
#pragma unroll
    for (int mt = 0; mt < MT; ++mt) {
        m_i[mt] = -1e30f;
#pragma unroll
        for (int r = 0; r < 16; ++r) { oL[mt][r] = 0.0f; oH[mt][r] = 0.0f; ol[mt][r] = 0.0f; }
    }

    stage(0, 0);
    __syncthreads();

    const int nIter = SKH / BK;   // 8
    for (int kt = 0; kt < nIter; ++kt) {
        const int buf = kt & 1;
        if (kt + 1 < nIter) stage(kt + 1, buf ^ 1);   // DMA in flight during compute

        // ---- kf reads: ONCE per kt, shared by both M-tiles ----
        f16x8 kf0[4], kf1[4];
#pragma unroll
        for (int ds = 0; ds < 4; ++ds) {
            kf0[ds] = *(const f16x8*)&sK[buf][offA[ds]];
            kf1[ds] = *(const f16x8*)&sK[buf][offA[ds] + 2048];
        }

        // ---- QK phase: all 16 MFMAs clustered (both M-tiles) ----
        f32x16 s0[MT], s1[MT];
#pragma unroll
        for (int mt = 0; mt < MT; ++mt)
#pragma unroll
            for (int r = 0; r < 16; ++r) { s0[mt][r] = 0.0f; s1[mt][r] = 0.0f; }

        __builtin_amdgcn_s_setprio(1);
#pragma unroll
        for (int ds = 0; ds < 4; ++ds)
#pragma unroll
            for (int mt = 0; mt < MT; ++mt) {
                s0[mt] = __builtin_amdgcn_mfma_f32_32x32x16_f16(kf0[ds], qf[mt][ds], s0[mt], 0, 0, 0);
                s1[mt] = __builtin_amdgcn_mfma_f32_32x32x16_f16(kf1[ds], qf[mt][ds], s1[mt], 0, 0, 0);
            }
        __builtin_amdgcn_s_setprio(0);

        // ---- vf reads (DS overlaps softmax VALU) ----
        f16x8 vf[4][2];
#pragma unroll
        for (int s = 0; s < 4; ++s) {
            vf[s][0] = *(const f16x8*)&sV[buf][offA[s]];
            vf[s][1] = *(const f16x8*)&sV[buf][offA[s] + 2048];
        }

#pragma unroll
        for (int mt = 0; mt < MT; ++mt) {
            // ---- in-register softmax: in-lane max tree + VALU cross-half ----
            float t[16];
#pragma unroll
            for (int r = 0; r < 16; ++r) t[r] = fmaxf(s0[mt][r], s1[mt][r]);
#pragma unroll
            for (int r = 0; r < 8; ++r)  t[r] = fmaxf(t[r], t[r + 8]);
#pragma unroll
            for (int r = 0; r < 4; ++r)  t[r] = fmaxf(t[r], t[r + 4]);
            float rm = fmaxf(fmaxf(t[0], t[1]), fmaxf(t[2], t[3]));
            rm = xhalf_max(rm);     // combine hi-halves of row q (permlane, VALU)

            // T13 defer-max: only rescale when some row's max grew > THR
            if (!__all(rm <= m_i[mt] + kDeferThr)) {
                const float mnew  = fmaxf(m_i[mt], rm);
                const float alpha = __builtin_amdgcn_exp2f(m_i[mt] - mnew);
                ol[mt][0] *= alpha;
#pragma unroll
                for (int r = 0; r < 16; ++r) { oL[mt][r] *= alpha; oH[mt][r] *= alpha; }
                m_i[mt] = mnew;
            }

#pragma unroll
            for (int r = 0; r < 16; ++r) {
                s0[mt][r] = __builtin_amdgcn_exp2f(s0[mt][r] - m_i[mt]);
                s1[mt][r] = __builtin_amdgcn_exp2f(s1[mt][r] - m_i[mt]);
            }

            // ---- P -> fp16 fragments (register-only, no LDS) ----
            f16x8 pa[4];
            PA_SLICE(pa[0], s0[mt], 0);   // keys  0-15
            PA_SLICE(pa[1], s0[mt], 8);   // keys 16-31
            PA_SLICE(pa[2], s1[mt], 0);   // keys 32-47
            PA_SLICE(pa[3], s1[mt], 8);   // keys 48-63

            // ---- PV + fused l: O^T += V^T P^T ; l += 1^T P^T ----
            __builtin_amdgcn_s_setprio(1);
#pragma unroll
            for (int s = 0; s < 4; ++s) {
                oL[mt] = __builtin_amdgcn_mfma_f32_32x32x16_f16(vf[s][0], pa[s], oL[mt], 0, 0, 0);
                oH[mt] = __builtin_amdgcn_mfma_f32_32x32x16_f16(vf[s][1], pa[s], oH[mt], 0, 0, 0);
                ol[mt] = __builtin_amdgcn_mfma_f32_32x32x16_f16(ones,     pa[s], ol[mt], 0, 0, 0);
            }
            __builtin_amdgcn_s_setprio(0);
        }

        __syncthreads();   // drains prefetch DMA (vmcnt) + LDS
    }

    // ---- epilogue: o reg r holds O[d = (r&3)+8*(r>>2)+4*hi (+32 for oH)][q].
    //      l = ol[mt][0] (MFMA summed both hi-halves). Ap stored NORMALIZED. ----
    _Float16* Ab = Ap + (size_t)ks * APART + ((size_t)b * kSQ + qb) * kD;
    float2* MLb = MLp + (size_t)ks * kB * kSQ + (size_t)b * kSQ + qb;
#pragma unroll
    for (int mt = 0; mt < MT; ++mt) {
        const int q = w * 64 + mt * 32 + l31;
        const float lf = ol[mt][0];
        const float inv = 1.0f / lf;
        _Float16* arow = &Ab[(size_t)q * kD];
#pragma unroll
        for (int g = 0; g < 4; ++g) {
            *(f16x4*)&arow[g * 8 + hi * 4] =
                pack4(oL[mt][4 * g] * inv, oL[mt][4 * g + 1] * inv,
                      oL[mt][4 * g + 2] * inv, oL[mt][4 * g + 3] * inv);
            *(f16x4*)&arow[32 + g * 8 + hi * 4] =
                pack4(oH[mt][4 * g] * inv, oH[mt][4 * g + 1] * inv,
                      oH[mt][4 * g + 2] * inv, oH[mt][4 * g + 3] * inv);
        }
        if (hi == 0) MLb[q] = make_float2(m_i[mt], lf);
    }
}

// ---------------- combine (exp2 domain; Ap normalized, weight = e*l) ----------------
__global__ __launch_bounds__(256)
void fattn_combine(const _Float16* __restrict__ Ap,
                   const float2* __restrict__ MLp,
                   float* __restrict__ Og)
{
    const int idx = blockIdx.x * 256 + threadIdx.x;
    const int r = idx >> 4;
    const int c = (idx & 15) * 4;

    float m = -1e30f;
    float2 ml[KSPLIT];
#pragma unroll
    for (int s = 0; s < KSPLIT; ++s) {
        ml[s] = MLp[(size_t)s * kB * kSQ + r];
        m = fmaxf(m, ml[s].x);
    }
    float acc[4] = {0.f, 0.f, 0.f, 0.f};
    float lsum = 0.f;
#pragma unroll
    for (int s = 0; s < KSPLIT; ++s) {
        const float wgt = __builtin_amdgcn_exp2f(ml[s].x - m) * ml[s].y;
        lsum += wgt;
        const f16x4 a = *(const f16x4*)&Ap[(size_t)s * APART + (size_t)r * kD + c];
#pragma unroll
        for (int j = 0; j < 4; ++j) acc[j] += wgt * (float)a[j];
    }
    const float inv = 1.0f / lsum;
    float4 res = make_float4(acc[0] * inv, acc[1] * inv, acc[2] * inv, acc[3] * inv);
    *(float4*)&Og[(size_t)r * kD + c] = res;
}

extern "C" void kernel_launch(void* const* d_in, const int* in_sizes, int n_in,
                              void* d_out, int out_size, void* d_ws, size_t ws_size,
                              hipStream_t stream) {
    const float* Q    = (const float*)d_in[0];
    const float* K    = (const float*)d_in[1];
    const float* V    = (const float*)d_in[2];
    const float* sdiv = (const float*)d_in[4];
    float* O = (float*)d_out;

    // workspace: Kh 4MB | Vt 4MB | Ap fp16 33.6MB | MLp 2MB (total ~43.6MB)
    _Float16* Kh  = (_Float16*)d_ws;
    _Float16* Vt  = Kh + (size_t)kB * kSK * kD;
    _Float16* Ap  = Vt + (size_t)kB * kSK * kD;
    float2*   MLp = (float2*)(Ap + (size_t)KSPLIT * APART);

    fattn_prepass<<<dim3(kSK / BK, kB), dim3(256), 0, stream>>>(K, V, Kh, Vt);
    fattn_partial<<<dim3((kSQ / BQ) * kB * KSPLIT), dim3(256), 0, stream>>>(Q, Kh, Vt, sdiv, Ap, MLp);
    fattn_combine<<<dim3(kB * kSQ * kD / (256 * 4)), dim3(256), 0, stream>>>(Ap, MLp, O);
}

// Round 9
// 137.075 us; speedup vs baseline: 3.5235x; 3.5235x over previous
//
#include <hip/hip_runtime.h>

// Flash attention forward, fp32 in/out, fp16 MFMA compute.
// B=8, SQ=SK=4096, D=64. scores = (Q/x5) K^T ; softmax ; O = P V.
// R24 = R16 (reverted from R22) + two-phase kt body.
// R22 post-mortem: KSPLIT=8 @ launch_bounds(256,4) spilled (VGPR cap 128 <
// ~190 actual incl AGPR accs) -> scratch FETCH 779MB, 419us. Occupancy path
// is dead (R11, R14, R22): >2 waves/SIMD needs <=128 regs = gutting MT=2.
// R16 profile: VALU 40 + Mfma 28 at 2 waves/SIMD, ~45% dependency bubbles in
// the serial per-kt chain run twice (once per mt). R24 restructures for
// cross-mt overlap at zero new work:
//  - Phase A: BOTH fmax trees (2 independent chains interleave), ONE combined
//    __all vote for both mts, then all 128 exp2 as one trans-pipe burst.
//  - Phase B: both PA packs, then ALL 48 PV MFMAs as one setprio cluster.
//  - vf reads moved to Phase B (frees regs in softmax; wait hides under pack).
// Kept: KSPLIT=4, MT=2/BQ=256, kf/vf once per kt, fused-l ones-MFMA,
// permlane cross-half max, defer-max THR=11.5, normalized Ap, dbuf
// global_load_lds staging, XCD-affine grid, launch_bounds(256,2).

typedef _Float16 f16x8 __attribute__((ext_vector_type(8)));
typedef _Float16 f16x4 __attribute__((ext_vector_type(4)));
typedef __fp16   h16x2 __attribute__((ext_vector_type(2)));
typedef float    f32x4 __attribute__((ext_vector_type(4)));
typedef float    f32x16 __attribute__((ext_vector_type(16)));

constexpr int kB  = 8;
constexpr int kSQ = 4096;
constexpr int kSK = 4096;
constexpr int kD  = 64;
constexpr int KSPLIT = 4;
constexpr int SKH = kSK / KSPLIT;     // 1024 keys per split
constexpr int BQ  = 256;              // 4 waves x 2 M-tiles x 32 Q rows
constexpr int MT  = 2;
constexpr int BK  = 64;
constexpr size_t APART = (size_t)kB * kSQ * kD;
constexpr float kLog2e = 1.44269504088896340736f;
constexpr float kDeferThr = 11.5f;    // exp2-domain (~8 nats); P <= 2^11.5

static __device__ __forceinline__ f16x4 pack4(float a, float b, float c, float d) {
    h16x2 p0 = __builtin_amdgcn_cvt_pkrtz(a, b);
    h16x2 p1 = __builtin_amdgcn_cvt_pkrtz(c, d);
    f16x4 r;
    r[0] = (_Float16)p0[0]; r[1] = (_Float16)p0[1];
    r[2] = (_Float16)p1[0]; r[3] = (_Float16)p1[1];
    return r;
}
static __device__ __forceinline__ f16x8 pack8(const float4& a, const float4& c) {
    f16x4 lo = pack4(a.x, a.y, a.z, a.w);
    f16x4 hi = pack4(c.x, c.y, c.z, c.w);
    f16x8 f;
    f[0] = lo[0]; f[1] = lo[1]; f[2] = lo[2]; f[3] = lo[3];
    f[4] = hi[0]; f[5] = hi[1]; f[6] = hi[2]; f[7] = hi[3];
    return f;
}
static __device__ __forceinline__ unsigned pkrtz_u(float a, float b) {
    union { h16x2 h; unsigned u; } cv;
    cv.h = __builtin_amdgcn_cvt_pkrtz(a, b);
    return cv.u;
}
static __device__ __forceinline__ float xhalf_max(float x) {
    // max(x[lane], x[lane^32]) in every lane, VALU-only.
    union { float f; unsigned u; } uv; uv.f = x;
    auto pr = __builtin_amdgcn_permlane32_swap(uv.u, uv.u, false, false);
    union { unsigned u; float f; } r0, r1;
    r0.u = pr[0]; r1.u = pr[1];
    return fmaxf(r0.f, r1.f);
}

typedef const __attribute__((address_space(1))) unsigned int* gu32p;
typedef __attribute__((address_space(3))) unsigned int* lu32p;
static __device__ __forceinline__ void gload_lds16(const void* g, void* l) {
    __builtin_amdgcn_global_load_lds((gu32p)g, (lu32p)l, 16, 0, 0);
}

// P slice (8 regs of one 32-key C-block) -> f16x8 PV fragment.
// C/D rows: key = (r&3)+8*(r>>2)+4*hi. Pair cvtpk(p[2i],p[2i+1]) with
// cvtpk(p[2i+4],p[2i+5]); one permlane32_swap fills two output words.
#define PA_SLICE(dst, sv, rb) do {                                          \
    unsigned c0 = pkrtz_u((sv)[(rb)+0], (sv)[(rb)+1]);                      \
    unsigned c1 = pkrtz_u((sv)[(rb)+2], (sv)[(rb)+3]);                      \
    unsigned c2 = pkrtz_u((sv)[(rb)+4], (sv)[(rb)+5]);                      \
    unsigned c3 = pkrtz_u((sv)[(rb)+6], (sv)[(rb)+7]);                      \
    auto r02 = __builtin_amdgcn_permlane32_swap(c0, c2, false, false);      \
    auto r13 = __builtin_amdgcn_permlane32_swap(c1, c3, false, false);      \
    union { unsigned u[4]; f16x8 v; } _r;                                   \
    _r.u[0] = r02[0]; _r.u[1] = r13[0]; _r.u[2] = r02[1]; _r.u[3] = r13[1]; \
    dst = _r.v;                                                             \
} while (0)

// ---------------- pre-pass: K -> Kh (swizzled fp16), V -> Vt (transposed,
// tiled, swizzled fp16). Kh[b][k][blk fb^(k&7)][8]; Vt[b][kt][f][blk kb^(f&7)][8].
__global__ __launch_bounds__(256, 2)
void fattn_prepass(const float* __restrict__ Kg,
                   const float* __restrict__ Vg,
                   _Float16* __restrict__ Kh,
                   _Float16* __restrict__ Vt)
{
    __shared__ _Float16 tr[kD][BK];

    const int tid = threadIdx.x;
    const int kt  = blockIdx.x;
    const int b   = blockIdx.y;

    const int k = tid >> 2;
    const int p = tid & 3;
    const int gk = kt * BK + k;

    {
        const float* src = Kg + ((size_t)b * kSK + gk) * kD + p * 16;
        const float4 a0 = *(const float4*)(src + 0);
        const float4 a1 = *(const float4*)(src + 4);
        const float4 a2 = *(const float4*)(src + 8);
        const float4 a3 = *(const float4*)(src + 12);
        _Float16* dst = Kh + ((size_t)b * kSK + gk) * kD;
        const int fb0 = 2 * p, fb1 = 2 * p + 1;
        *(f16x8*)&dst[(fb0 ^ (gk & 7)) * 8] = pack8(a0, a1);
        *(f16x8*)&dst[(fb1 ^ (gk & 7)) * 8] = pack8(a2, a3);
    }
    {
        const float* src = Vg + ((size_t)b * kSK + gk) * kD + p * 16;
        const float4 a0 = *(const float4*)(src + 0);
        const float4 a1 = *(const float4*)(src + 4);
        const float4 a2 = *(const float4*)(src + 8);
        const float4 a3 = *(const float4*)(src + 12);
        const float v[16] = {a0.x,a0.y,a0.z,a0.w, a1.x,a1.y,a1.z,a1.w,
                             a2.x,a2.y,a2.z,a2.w, a3.x,a3.y,a3.z,a3.w};
#pragma unroll
        for (int j = 0; j < 16; ++j)
            tr[p * 16 + j][k] = (_Float16)v[j];
    }
    __syncthreads();
    {
        const int f  = tid >> 2;
        const int p2 = tid & 3;
        const f16x8 b0 = *(const f16x8*)&tr[f][p2 * 16 + 0];
        const f16x8 b1 = *(const f16x8*)&tr[f][p2 * 16 + 8];
        _Float16* dst = Vt + (((size_t)b * 64 + kt) * kD + f) * BK;
        const int kb0 = 2 * p2, kb1 = 2 * p2 + 1;
        *(f16x8*)&dst[(kb0 ^ (f & 7)) * 8] = b0;
        *(f16x8*)&dst[(kb1 ^ (f & 7)) * 8] = b1;
    }
}

// ---------------- main partial kernel (32x32x16 MFMA, MT=2, two-phase) ----------------
__global__ __launch_bounds__(256, 2)
void fattn_partial(const float* __restrict__ Qg,
                   const _Float16* __restrict__ Kh,
                   const _Float16* __restrict__ Vt,
                   const float* __restrict__ sdiv,
                   _Float16* __restrict__ Ap,   // [KSPLIT][B][SQ][D] NORMALIZED (O/l)
                   float2* __restrict__ MLp)    // [KSPLIT][B][SQ] (m,l) exp2-domain
{
    __shared__ __align__(16) _Float16 sK[2][BK * kD];   // 16 KB
    __shared__ __align__(16) _Float16 sV[2][kD * BK];   // 16 KB

    const int tid  = threadIdx.x;
    const int w    = tid >> 6;
    const int lane = tid & 63;
    const int l31  = lane & 31;
    const int hi   = lane >> 5;

    // XCD-affine decode: flat = c + 32*q; c = (b,ks); all 16 q-blocks of one
    // K/V stream share an XCD (flat%8 invariant across q).
    const int flat = blockIdx.x;
    const int c    = flat & 31;
    const int qi   = flat >> 5;
    const int b    = c >> 2;      // KSPLIT = 4
    const int ks   = c & 3;
    const int qb   = qi * BQ;

    const float qscale = kLog2e / sdiv[0];   // exp2 domain

    const float* Qb = Qg + ((size_t)b * kSQ + qb) * kD;
    const _Float16* Khb = Kh + ((size_t)b * kSK + (size_t)ks * SKH) * kD;
    const _Float16* Vtb = Vt + (((size_t)b * 64 + (size_t)ks * (SKH / BK)) * kD) * BK;

    // ---- Q fragments: qf[mt][ds][j] = Q[q][ds*16 + hi*8 + j]*qscale,
    //      q = qb + w*64 + mt*32 + l31 (lane-col of all MFMAs) ----
    f16x8 qf[MT][4];
#pragma unroll
    for (int mt = 0; mt < MT; ++mt) {
        const float* qrow = Qb + (size_t)(w * 64 + mt * 32 + l31) * kD;
#pragma unroll
        for (int ds = 0; ds < 4; ++ds) {
            const float4 a  = *(const float4*)(qrow + ds * 16 + hi * 8);
            const float4 cc = *(const float4*)(qrow + ds * 16 + hi * 8 + 4);
            float4 as = make_float4(a.x * qscale, a.y * qscale, a.z * qscale, a.w * qscale);
            float4 cs = make_float4(cc.x * qscale, cc.y * qscale, cc.z * qscale, cc.w * qscale);
            qf[mt][ds] = pack8(as, cs);
        }
    }

    // ones A-fragment for the fused-l MFMA
    f16x8 ones;
#pragma unroll
    for (int j = 0; j < 8; ++j) ones[j] = (_Float16)1.0f;

    // Swizzled LDS fragment offsets (halves); identical pattern for K and V:
    // row = l31 (+32 for second block), 16B slot = (2*i + hi) ^ (row & 7).
    int offA[4];
#pragma unroll
    for (int i = 0; i < 4; ++i)
        offA[i] = l31 * 64 + (((2 * i + hi) ^ (l31 & 7)) * 8);

    // ---- async staging: 4 global_load_lds per wave ----
    auto stage = [&](int kt, int buf) {
        const char* gk = (const char*)(Khb + (size_t)kt * BK * kD) + w * 2048 + lane * 16;
        const char* gv = (const char*)(Vtb + (size_t)kt * kD * BK) + w * 2048 + lane * 16;
        char* lk = (char*)&sK[buf][0] + w * 2048;
        char* lv = (char*)&sV[buf][0] + w * 2048;
        gload_lds16(gk,        lk);
        gload_lds16(gk + 1024, lk + 1024);
        gload_lds16(gv,        lv);
        gload_lds16(gv + 1024, lv + 1024);
    };

    f32x16 oL[MT], oH[MT];         // O^T accumulators: d rows 0-31 / 32-63
    f32x16 ol[MT];                 // fused-l accumulator (only [0] consumed)
    float m_i[MT];
#pragma unroll
    for (int mt = 0; mt < MT; ++mt) {
        m_i[mt] = -1e30f;
#pragma unroll
        for (int r = 0; r < 16; ++r) { oL[mt][r] = 0.0f; oH[mt][r] = 0.0f; ol[mt][r] = 0.0f; }
    }

    stage(0, 0);
    __syncthreads();

    const int nIter = SKH / BK;   // 16
    for (int kt = 0; kt < nIter; ++kt) {
        const int buf = kt & 1;
        if (kt + 1 < nIter) stage(kt + 1, buf ^ 1);   // DMA in flight during compute

        // ---- kf reads: ONCE per kt, shared by both M-tiles ----
        f16x8 kf0[4], kf1[4];
#pragma unroll
        for (int ds = 0; ds < 4; ++ds) {
            kf0[ds] = *(const f16x8*)&sK[buf][offA[ds]];
            kf1[ds] = *(const f16x8*)&sK[buf][offA[ds] + 2048];
        }

        // ---- QK phase: all 16 MFMAs clustered (both M-tiles) ----
        f32x16 s0[MT], s1[MT];
#pragma unroll
        for (int mt = 0; mt < MT; ++mt)
#pragma unroll
            for (int r = 0; r < 16; ++r) { s0[mt][r] = 0.0f; s1[mt][r] = 0.0f; }

        __builtin_amdgcn_s_setprio(1);
#pragma unroll
        for (int ds = 0; ds < 4; ++ds)
#pragma unroll
            for (int mt = 0; mt < MT; ++mt) {
                s0[mt] = __builtin_amdgcn_mfma_f32_32x32x16_f16(kf0[ds], qf[mt][ds], s0[mt], 0, 0, 0);
                s1[mt] = __builtin_amdgcn_mfma_f32_32x32x16_f16(kf1[ds], qf[mt][ds], s1[mt], 0, 0, 0);
            }
        __builtin_amdgcn_s_setprio(0);

        // ---- PHASE A: both softmaxes together (2 independent chains) ----
        float rm0, rm1;
        {
            float t0[16], t1[16];
#pragma unroll
            for (int r = 0; r < 16; ++r) { t0[r] = fmaxf(s0[0][r], s1[0][r]);
                                           t1[r] = fmaxf(s0[1][r], s1[1][r]); }
#pragma unroll
            for (int r = 0; r < 8; ++r)  { t0[r] = fmaxf(t0[r], t0[r + 8]);
                                           t1[r] = fmaxf(t1[r], t1[r + 8]); }
#pragma unroll
            for (int r = 0; r < 4; ++r)  { t0[r] = fmaxf(t0[r], t0[r + 4]);
                                           t1[r] = fmaxf(t1[r], t1[r + 4]); }
            rm0 = fmaxf(fmaxf(t0[0], t0[1]), fmaxf(t0[2], t0[3]));
            rm1 = fmaxf(fmaxf(t1[0], t1[1]), fmaxf(t1[2], t1[3]));
            rm0 = xhalf_max(rm0);
            rm1 = xhalf_max(rm1);
        }

        // T13 defer-max: single combined vote for both M-tiles
        if (!__all(rm0 <= m_i[0] + kDeferThr && rm1 <= m_i[1] + kDeferThr)) {
            {
                const float mnew  = fmaxf(m_i[0], rm0);
                const float alpha = __builtin_amdgcn_exp2f(m_i[0] - mnew);
                ol[0][0] *= alpha;
#pragma unroll
                for (int r = 0; r < 16; ++r) { oL[0][r] *= alpha; oH[0][r] *= alpha; }
                m_i[0] = mnew;
            }
            {
                const float mnew  = fmaxf(m_i[1], rm1);
                const float alpha = __builtin_amdgcn_exp2f(m_i[1] - mnew);
                ol[1][0] *= alpha;
#pragma unroll
                for (int r = 0; r < 16; ++r) { oL[1][r] *= alpha; oH[1][r] *= alpha; }
                m_i[1] = mnew;
            }
        }

        // all 128 exp2 as one uninterrupted trans-pipe burst
#pragma unroll
        for (int r = 0; r < 16; ++r) {
            s0[0][r] = __builtin_amdgcn_exp2f(s0[0][r] - m_i[0]);
            s1[0][r] = __builtin_amdgcn_exp2f(s1[0][r] - m_i[0]);
            s0[1][r] = __builtin_amdgcn_exp2f(s0[1][r] - m_i[1]);
            s1[1][r] = __builtin_amdgcn_exp2f(s1[1][r] - m_i[1]);
        }

        // ---- PHASE B: vf reads, both PA packs, one 48-MFMA PV cluster ----
        f16x8 vf[4][2];
#pragma unroll
        for (int s = 0; s < 4; ++s) {
            vf[s][0] = *(const f16x8*)&sV[buf][offA[s]];
            vf[s][1] = *(const f16x8*)&sV[buf][offA[s] + 2048];
        }

        f16x8 pa0[4], pa1[4];
        PA_SLICE(pa0[0], s0[0], 0);  PA_SLICE(pa0[1], s0[0], 8);
        PA_SLICE(pa0[2], s1[0], 0);  PA_SLICE(pa0[3], s1[0], 8);
        PA_SLICE(pa1[0], s0[1], 0);  PA_SLICE(pa1[1], s0[1], 8);
        PA_SLICE(pa1[2], s1[1], 0);  PA_SLICE(pa1[3], s1[1], 8);

        __builtin_amdgcn_s_setprio(1);
#pragma unroll
        for (int s = 0; s < 4; ++s) {
            oL[0] = __builtin_amdgcn_mfma_f32_32x32x16_f16(vf[s][0], pa0[s], oL[0], 0, 0, 0);
            oH[0] = __builtin_amdgcn_mfma_f32_32x32x16_f16(vf[s][1], pa0[s], oH[0], 0, 0, 0);
            oL[1] = __builtin_amdgcn_mfma_f32_32x32x16_f16(vf[s][0], pa1[s], oL[1], 0, 0, 0);
            oH[1] = __builtin_amdgcn_mfma_f32_32x32x16_f16(vf[s][1], pa1[s], oH[1], 0, 0, 0);
            ol[0] = __builtin_amdgcn_mfma_f32_32x32x16_f16(ones,     pa0[s], ol[0], 0, 0, 0);
            ol[1] = __builtin_amdgcn_mfma_f32_32x32x16_f16(ones,     pa1[s], ol[1], 0, 0, 0);
        }
        __builtin_amdgcn_s_setprio(0);

        __syncthreads();   // drains prefetch DMA (vmcnt) + LDS
    }

    // ---- epilogue: o reg r holds O[d = (r&3)+8*(r>>2)+4*hi (+32 for oH)][q].
    //      l = ol[mt][0] (MFMA summed both hi-halves). Ap stored NORMALIZED. ----
    _Float16* Ab = Ap + (size_t)ks * APART + ((size_t)b * kSQ + qb) * kD;
    float2* MLb = MLp + (size_t)ks * kB * kSQ + (size_t)b * kSQ + qb;
#pragma unroll
    for (int mt = 0; mt < MT; ++mt) {
        const int q = w * 64 + mt * 32 + l31;
        const float lf = ol[mt][0];
        const float inv = 1.0f / lf;
        _Float16* arow = &Ab[(size_t)q * kD];
#pragma unroll
        for (int g = 0; g < 4; ++g) {
            *(f16x4*)&arow[g * 8 + hi * 4] =
                pack4(oL[mt][4 * g] * inv, oL[mt][4 * g + 1] * inv,
                      oL[mt][4 * g + 2] * inv, oL[mt][4 * g + 3] * inv);
            *(f16x4*)&arow[32 + g * 8 + hi * 4] =
                pack4(oH[mt][4 * g] * inv, oH[mt][4 * g + 1] * inv,
                      oH[mt][4 * g + 2] * inv, oH[mt][4 * g + 3] * inv);
        }
        if (hi == 0) MLb[q] = make_float2(m_i[mt], lf);
    }
}

// ---------------- combine (exp2 domain; Ap normalized, weight = e*l) ----------------
__global__ __launch_bounds__(256)
void fattn_combine(const _Float16* __restrict__ Ap,
                   const float2* __restrict__ MLp,
                   float* __restrict__ Og)
{
    const int idx = blockIdx.x * 256 + threadIdx.x;
    const int r = idx >> 4;
    const int c = (idx & 15) * 4;

    float m = -1e30f;
    float2 ml[KSPLIT];
#pragma unroll
    for (int s = 0; s < KSPLIT; ++s) {
        ml[s] = MLp[(size_t)s * kB * kSQ + r];
        m = fmaxf(m, ml[s].x);
    }
    float acc[4] = {0.f, 0.f, 0.f, 0.f};
    float lsum = 0.f;
#pragma unroll
    for (int s = 0; s < KSPLIT; ++s) {
        const float wgt = __builtin_amdgcn_exp2f(ml[s].x - m) * ml[s].y;
        lsum += wgt;
        const f16x4 a = *(const f16x4*)&Ap[(size_t)s * APART + (size_t)r * kD + c];
#pragma unroll
        for (int j = 0; j < 4; ++j) acc[j] += wgt * (float)a[j];
    }
    const float inv = 1.0f / lsum;
    float4 res = make_float4(acc[0] * inv, acc[1] * inv, acc[2] * inv, acc[3] * inv);
    *(float4*)&Og[(size_t)r * kD + c] = res;
}

extern "C" void kernel_launch(void* const* d_in, const int* in_sizes, int n_in,
                              void* d_out, int out_size, void* d_ws, size_t ws_size,
                              hipStream_t stream) {
    const float* Q    = (const float*)d_in[0];
    const float* K    = (const float*)d_in[1];
    const float* V    = (const float*)d_in[2];
    const float* sdiv = (const float*)d_in[4];
    float* O = (float*)d_out;

    // workspace: Kh 4MB | Vt 4MB | Ap fp16 16.8MB | MLp 1MB
    _Float16* Kh  = (_Float16*)d_ws;
    _Float16* Vt  = Kh + (size_t)kB * kSK * kD;
    _Float16* Ap  = Vt + (size_t)kB * kSK * kD;
    float2*   MLp = (float2*)(Ap + (size_t)KSPLIT * APART);

    fattn_prepass<<<dim3(kSK / BK, kB), dim3(256), 0, stream>>>(K, V, Kh, Vt);
    fattn_partial<<<dim3((kSQ / BQ) * kB * KSPLIT), dim3(256), 0, stream>>>(Q, Kh, Vt, sdiv, Ap, MLp);
    fattn_combine<<<dim3(kB * kSQ * kD / (256 * 4)), dim3(256), 0, stream>>>(Ap, MLp, O);
}

// Round 10
// 134.964 us; speedup vs baseline: 3.5786x; 1.0156x over previous
//
#include <hip/hip_runtime.h>

// Flash attention forward, fp32 in/out, fp16 MFMA compute.
// B=8, SQ=SK=4096, D=64. scores = (Q/x5) K^T ; softmax ; O = P V.
// R26 = R16 body (61.0us best; R24's phase-clustering reverted: 65.4) with
// TK=128 key tiles: two 64-key sub-steps per staged tile, ONE barrier per
// 128 keys (8 barriers instead of 16). Accounting: wall 4578cy/wave-kt =
// MFMA 1280 (28% ✓) + VALU/trans 1600 (35% ✓) + ~1400 fixed (barrier drain/
// skew, lgkm at kt head, vote) paid 16x -> halve the fixed events.
// LDS 64KB/block (2 blocks/CU = 128 <= 160KB, occupancy unchanged);
// registers unchanged (sub-steps reuse the same live set); Kh/Vt layouts
// already contiguous over 128 keys -> staging stays linear (8 loads/wave).
// Kept: 32x32x16 swapped QK^T, in-register mt-interleaved softmax, permlane
// P redistribution, fused-l ones-MFMA, kf/vf once per sub-step, defer-max
// THR=11.5, normalized Ap, XCD-affine grid, launch_bounds(256,2), KSPLIT=4.

typedef _Float16 f16x8 __attribute__((ext_vector_type(8)));
typedef _Float16 f16x4 __attribute__((ext_vector_type(4)));
typedef __fp16   h16x2 __attribute__((ext_vector_type(2)));
typedef float    f32x4 __attribute__((ext_vector_type(4)));
typedef float    f32x16 __attribute__((ext_vector_type(16)));

constexpr int kB  = 8;
constexpr int kSQ = 4096;
constexpr int kSK = 4096;
constexpr int kD  = 64;
constexpr int KSPLIT = 4;
constexpr int SKH = kSK / KSPLIT;     // 1024 keys per split
constexpr int BQ  = 256;              // 4 waves x 2 M-tiles x 32 Q rows
constexpr int MT  = 2;
constexpr int BK  = 64;               // prepass tile / Vt 64-key tile unit
constexpr int TK  = 128;              // main-loop staged tile (2 sub-steps)
constexpr size_t APART = (size_t)kB * kSQ * kD;
constexpr float kLog2e = 1.44269504088896340736f;
constexpr float kDeferThr = 11.5f;    // exp2-domain (~8 nats); P <= 2^11.5

static __device__ __forceinline__ f16x4 pack4(float a, float b, float c, float d) {
    h16x2 p0 = __builtin_amdgcn_cvt_pkrtz(a, b);
    h16x2 p1 = __builtin_amdgcn_cvt_pkrtz(c, d);
    f16x4 r;
    r[0] = (_Float16)p0[0]; r[1] = (_Float16)p0[1];
    r[2] = (_Float16)p1[0]; r[3] = (_Float16)p1[1];
    return r;
}
static __device__ __forceinline__ f16x8 pack8(const float4& a, const float4& c) {
    f16x4 lo = pack4(a.x, a.y, a.z, a.w);
    f16x4 hi = pack4(c.x, c.y, c.z, c.w);
    f16x8 f;
    f[0] = lo[0]; f[1] = lo[1]; f[2] = lo[2]; f[3] = lo[3];
    f[4] = hi[0]; f[5] = hi[1]; f[6] = hi[2]; f[7] = hi[3];
    return f;
}
static __device__ __forceinline__ unsigned pkrtz_u(float a, float b) {
    union { h16x2 h; unsigned u; } cv;
    cv.h = __builtin_amdgcn_cvt_pkrtz(a, b);
    return cv.u;
}
static __device__ __forceinline__ float xhalf_max(float x) {
    // max(x[lane], x[lane^32]) in every lane, VALU-only.
    union { float f; unsigned u; } uv; uv.f = x;
    auto pr = __builtin_amdgcn_permlane32_swap(uv.u, uv.u, false, false);
    union { unsigned u; float f; } r0, r1;
    r0.u = pr[0]; r1.u = pr[1];
    return fmaxf(r0.f, r1.f);
}

typedef const __attribute__((address_space(1))) unsigned int* gu32p;
typedef __attribute__((address_space(3))) unsigned int* lu32p;
static __device__ __forceinline__ void gload_lds16(const void* g, void* l) {
    __builtin_amdgcn_global_load_lds((gu32p)g, (lu32p)l, 16, 0, 0);
}

// P slice (8 regs of one 32-key C-block) -> f16x8 PV fragment.
// C/D rows: key = (r&3)+8*(r>>2)+4*hi. Pair cvtpk(p[2i],p[2i+1]) with
// cvtpk(p[2i+4],p[2i+5]); one permlane32_swap fills two output words.
#define PA_SLICE(dst, sv, rb) do {                                          \
    unsigned c0 = pkrtz_u((sv)[(rb)+0], (sv)[(rb)+1]);                      \
    unsigned c1 = pkrtz_u((sv)[(rb)+2], (sv)[(rb)+3]);                      \
    unsigned c2 = pkrtz_u((sv)[(rb)+4], (sv)[(rb)+5]);                      \
    unsigned c3 = pkrtz_u((sv)[(rb)+6], (sv)[(rb)+7]);                      \
    auto r02 = __builtin_amdgcn_permlane32_swap(c0, c2, false, false);      \
    auto r13 = __builtin_amdgcn_permlane32_swap(c1, c3, false, false);      \
    union { unsigned u[4]; f16x8 v; } _r;                                   \
    _r.u[0] = r02[0]; _r.u[1] = r13[0]; _r.u[2] = r02[1]; _r.u[3] = r13[1]; \
    dst = _r.v;                                                             \
} while (0)

// ---------------- pre-pass: K -> Kh (swizzled fp16), V -> Vt (transposed,
// tiled, swizzled fp16). Kh[b][k][blk fb^(k&7)][8]; Vt[b][kt][f][blk kb^(f&7)][8].
__global__ __launch_bounds__(256, 2)
void fattn_prepass(const float* __restrict__ Kg,
                   const float* __restrict__ Vg,
                   _Float16* __restrict__ Kh,
                   _Float16* __restrict__ Vt)
{
    __shared__ _Float16 tr[kD][BK];

    const int tid = threadIdx.x;
    const int kt  = blockIdx.x;
    const int b   = blockIdx.y;

    const int k = tid >> 2;
    const int p = tid & 3;
    const int gk = kt * BK + k;

    {
        const float* src = Kg + ((size_t)b * kSK + gk) * kD + p * 16;
        const float4 a0 = *(const float4*)(src + 0);
        const float4 a1 = *(const float4*)(src + 4);
        const float4 a2 = *(const float4*)(src + 8);
        const float4 a3 = *(const float4*)(src + 12);
        _Float16* dst = Kh + ((size_t)b * kSK + gk) * kD;
        const int fb0 = 2 * p, fb1 = 2 * p + 1;
        *(f16x8*)&dst[(fb0 ^ (gk & 7)) * 8] = pack8(a0, a1);
        *(f16x8*)&dst[(fb1 ^ (gk & 7)) * 8] = pack8(a2, a3);
    }
    {
        const float* src = Vg + ((size_t)b * kSK + gk) * kD + p * 16;
        const float4 a0 = *(const float4*)(src + 0);
        const float4 a1 = *(const float4*)(src + 4);
        const float4 a2 = *(const float4*)(src + 8);
        const float4 a3 = *(const float4*)(src + 12);
        const float v[16] = {a0.x,a0.y,a0.z,a0.w, a1.x,a1.y,a1.z,a1.w,
                             a2.x,a2.y,a2.z,a2.w, a3.x,a3.y,a3.z,a3.w};
#pragma unroll
        for (int j = 0; j < 16; ++j)
            tr[p * 16 + j][k] = (_Float16)v[j];
    }
    __syncthreads();
    {
        const int f  = tid >> 2;
        const int p2 = tid & 3;
        const f16x8 b0 = *(const f16x8*)&tr[f][p2 * 16 + 0];
        const f16x8 b1 = *(const f16x8*)&tr[f][p2 * 16 + 8];
        _Float16* dst = Vt + (((size_t)b * 64 + kt) * kD + f) * BK;
        const int kb0 = 2 * p2, kb1 = 2 * p2 + 1;
        *(f16x8*)&dst[(kb0 ^ (f & 7)) * 8] = b0;
        *(f16x8*)&dst[(kb1 ^ (f & 7)) * 8] = b1;
    }
}

// ---------------- main partial kernel (32x32x16 MFMA, MT=2, TK=128) ----------------
__global__ __launch_bounds__(256, 2)
void fattn_partial(const float* __restrict__ Qg,
                   const _Float16* __restrict__ Kh,
                   const _Float16* __restrict__ Vt,
                   const float* __restrict__ sdiv,
                   _Float16* __restrict__ Ap,   // [KSPLIT][B][SQ][D] NORMALIZED (O/l)
                   float2* __restrict__ MLp)    // [KSPLIT][B][SQ] (m,l) exp2-domain
{
    __shared__ __align__(16) _Float16 sK[2][TK * kD];   // 32 KB
    __shared__ __align__(16) _Float16 sV[2][kD * TK];   // 32 KB

    const int tid  = threadIdx.x;
    const int w    = tid >> 6;
    const int lane = tid & 63;
    const int l31  = lane & 31;
    const int hi   = lane >> 5;

    // XCD-affine decode: flat = c + 32*q; c = (b,ks); all 16 q-blocks of one
    // K/V stream share an XCD (flat%8 invariant across q).
    const int flat = blockIdx.x;
    const int c    = flat & 31;
    const int qi   = flat >> 5;
    const int b    = c >> 2;      // KSPLIT = 4
    const int ks   = c & 3;
    const int qb   = qi * BQ;

    const float qscale = kLog2e / sdiv[0];   // exp2 domain

    const float* Qb = Qg + ((size_t)b * kSQ + qb) * kD;
    const _Float16* Khb = Kh + ((size_t)b * kSK + (size_t)ks * SKH) * kD;
    const _Float16* Vtb = Vt + (((size_t)b * 64 + (size_t)ks * (SKH / BK)) * kD) * BK;

    // ---- Q fragments: qf[mt][ds][j] = Q[q][ds*16 + hi*8 + j]*qscale,
    //      q = qb + w*64 + mt*32 + l31 (lane-col of all MFMAs) ----
    f16x8 qf[MT][4];
#pragma unroll
    for (int mt = 0; mt < MT; ++mt) {
        const float* qrow = Qb + (size_t)(w * 64 + mt * 32 + l31) * kD;
#pragma unroll
        for (int ds = 0; ds < 4; ++ds) {
            const float4 a  = *(const float4*)(qrow + ds * 16 + hi * 8);
            const float4 cc = *(const float4*)(qrow + ds * 16 + hi * 8 + 4);
            float4 as = make_float4(a.x * qscale, a.y * qscale, a.z * qscale, a.w * qscale);
            float4 cs = make_float4(cc.x * qscale, cc.y * qscale, cc.z * qscale, cc.w * qscale);
            qf[mt][ds] = pack8(as, cs);
        }
    }

    // ones A-fragment for the fused-l MFMA
    f16x8 ones;
#pragma unroll
    for (int j = 0; j < 8; ++j) ones[j] = (_Float16)1.0f;

    // Swizzled LDS fragment offsets (halves); identical pattern for K and V:
    // row = l31 (+32 for second block), 16B slot = (2*i + hi) ^ (row & 7).
    int offA[4];
#pragma unroll
    for (int i = 0; i < 4; ++i)
        offA[i] = l31 * 64 + (((2 * i + hi) ^ (l31 & 7)) * 8);

    // ---- async staging: 8 global_load_lds per wave (32KB tile: K 16KB + V 16KB) ----
    auto stage = [&](int kt, int buf) {
        const char* gk = (const char*)(Khb + (size_t)kt * TK * kD) + w * 4096 + lane * 16;
        const char* gv = (const char*)(Vtb + (size_t)kt * kD * TK) + w * 4096 + lane * 16;
        char* lk = (char*)&sK[buf][0] + w * 4096;
        char* lv = (char*)&sV[buf][0] + w * 4096;
        gload_lds16(gk,        lk);
        gload_lds16(gk + 1024, lk + 1024);
        gload_lds16(gk + 2048, lk + 2048);
        gload_lds16(gk + 3072, lk + 3072);
        gload_lds16(gv,        lv);
        gload_lds16(gv + 1024, lv + 1024);
        gload_lds16(gv + 2048, lv + 2048);
        gload_lds16(gv + 3072, lv + 3072);
    };

    f32x16 oL[MT], oH[MT];         // O^T accumulators: d rows 0-31 / 32-63
    f32x16 ol[MT];                 // fused-l accumulator (only [0] consumed)
    float m_i[MT];
#pragma unroll
    for (int mt = 0; mt < MT; ++mt) {
        m_i[mt] = -1e30f;
#pragma unroll
        for (int r = 0; r < 16; ++r) { oL[mt][r] = 0.0f; oH[mt][r] = 0.0f; ol[mt][r] = 0.0f; }
    }

    stage(0, 0);
    __syncthreads();

    const int nIter = SKH / TK;   // 8
    for (int kt = 0; kt < nIter; ++kt) {
        const int buf = kt & 1;
        if (kt + 1 < nIter) stage(kt + 1, buf ^ 1);   // DMA in flight during compute

#pragma unroll
        for (int sub = 0; sub < 2; ++sub) {
            const int sb = sub * (BK * kD);   // 4096-elem sub-tile offset

            // ---- kf reads: ONCE per sub-step, shared by both M-tiles ----
            f16x8 kf0[4], kf1[4];
#pragma unroll
            for (int ds = 0; ds < 4; ++ds) {
                kf0[ds] = *(const f16x8*)&sK[buf][sb + offA[ds]];
                kf1[ds] = *(const f16x8*)&sK[buf][sb + offA[ds] + 2048];
            }

            // ---- QK phase: all 16 MFMAs clustered (both M-tiles) ----
            f32x16 s0[MT], s1[MT];
#pragma unroll
            for (int mt = 0; mt < MT; ++mt)
#pragma unroll
                for (int r = 0; r < 16; ++r) { s0[mt][r] = 0.0f; s1[mt][r] = 0.0f; }

            __builtin_amdgcn_s_setprio(1);
#pragma unroll
            for (int ds = 0; ds < 4; ++ds)
#pragma unroll
                for (int mt = 0; mt < MT; ++mt) {
                    s0[mt] = __builtin_amdgcn_mfma_f32_32x32x16_f16(kf0[ds], qf[mt][ds], s0[mt], 0, 0, 0);
                    s1[mt] = __builtin_amdgcn_mfma_f32_32x32x16_f16(kf1[ds], qf[mt][ds], s1[mt], 0, 0, 0);
                }
            __builtin_amdgcn_s_setprio(0);

            // ---- vf reads (DS overlaps softmax VALU) ----
            f16x8 vf[4][2];
#pragma unroll
            for (int s = 0; s < 4; ++s) {
                vf[s][0] = *(const f16x8*)&sV[buf][sb + offA[s]];
                vf[s][1] = *(const f16x8*)&sV[buf][sb + offA[s] + 2048];
            }

#pragma unroll
            for (int mt = 0; mt < MT; ++mt) {
                // ---- in-register softmax: in-lane max tree + VALU cross-half ----
                float t[16];
#pragma unroll
                for (int r = 0; r < 16; ++r) t[r] = fmaxf(s0[mt][r], s1[mt][r]);
#pragma unroll
                for (int r = 0; r < 8; ++r)  t[r] = fmaxf(t[r], t[r + 8]);
#pragma unroll
                for (int r = 0; r < 4; ++r)  t[r] = fmaxf(t[r], t[r + 4]);
                float rm = fmaxf(fmaxf(t[0], t[1]), fmaxf(t[2], t[3]));
                rm = xhalf_max(rm);     // combine hi-halves of row q (permlane, VALU)

                // T13 defer-max: only rescale when some row's max grew > THR
                if (!__all(rm <= m_i[mt] + kDeferThr)) {
                    const float mnew  = fmaxf(m_i[mt], rm);
                    const float alpha = __builtin_amdgcn_exp2f(m_i[mt] - mnew);
                    ol[mt][0] *= alpha;
#pragma unroll
                    for (int r = 0; r < 16; ++r) { oL[mt][r] *= alpha; oH[mt][r] *= alpha; }
                    m_i[mt] = mnew;
                }

#pragma unroll
                for (int r = 0; r < 16; ++r) {
                    s0[mt][r] = __builtin_amdgcn_exp2f(s0[mt][r] - m_i[mt]);
                    s1[mt][r] = __builtin_amdgcn_exp2f(s1[mt][r] - m_i[mt]);
                }

                // ---- P -> fp16 fragments (register-only, no LDS) ----
                f16x8 pa[4];
                PA_SLICE(pa[0], s0[mt], 0);   // keys  0-15
                PA_SLICE(pa[1], s0[mt], 8);   // keys 16-31
                PA_SLICE(pa[2], s1[mt], 0);   // keys 32-47
                PA_SLICE(pa[3], s1[mt], 8);   // keys 48-63

                // ---- PV + fused l: O^T += V^T P^T ; l += 1^T P^T ----
                __builtin_amdgcn_s_setprio(1);
#pragma unroll
                for (int s = 0; s < 4; ++s) {
                    oL[mt] = __builtin_amdgcn_mfma_f32_32x32x16_f16(vf[s][0], pa[s], oL[mt], 0, 0, 0);
                    oH[mt] = __builtin_amdgcn_mfma_f32_32x32x16_f16(vf[s][1], pa[s], oH[mt], 0, 0, 0);
                    ol[mt] = __builtin_amdgcn_mfma_f32_32x32x16_f16(ones,     pa[s], ol[mt], 0, 0, 0);
                }
                __builtin_amdgcn_s_setprio(0);
            }
        }

        __syncthreads();   // one barrier per 128 keys: drains DMA + LDS reuse
    }

    // ---- epilogue: o reg r holds O[d = (r&3)+8*(r>>2)+4*hi (+32 for oH)][q].
    //      l = ol[mt][0] (MFMA summed both hi-halves). Ap stored NORMALIZED. ----
    _Float16* Ab = Ap + (size_t)ks * APART + ((size_t)b * kSQ + qb) * kD;
    float2* MLb = MLp + (size_t)ks * kB * kSQ + (size_t)b * kSQ + qb;
#pragma unroll
    for (int mt = 0; mt < MT; ++mt) {
        const int q = w * 64 + mt * 32 + l31;
        const float lf = ol[mt][0];
        const float inv = 1.0f / lf;
        _Float16* arow = &Ab[(size_t)q * kD];
#pragma unroll
        for (int g = 0; g < 4; ++g) {
            *(f16x4*)&arow[g * 8 + hi * 4] =
                pack4(oL[mt][4 * g] * inv, oL[mt][4 * g + 1] * inv,
                      oL[mt][4 * g + 2] * inv, oL[mt][4 * g + 3] * inv);
            *(f16x4*)&arow[32 + g * 8 + hi * 4] =
                pack4(oH[mt][4 * g] * inv, oH[mt][4 * g + 1] * inv,
                      oH[mt][4 * g + 2] * inv, oH[mt][4 * g + 3] * inv);
        }
        if (hi == 0) MLb[q] = make_float2(m_i[mt], lf);
    }
}

// ---------------- combine (exp2 domain; Ap normalized, weight = e*l) ----------------
__global__ __launch_bounds__(256)
void fattn_combine(const _Float16* __restrict__ Ap,
                   const float2* __restrict__ MLp,
                   float* __restrict__ Og)
{
    const int idx = blockIdx.x * 256 + threadIdx.x;
    const int r = idx >> 4;
    const int c = (idx & 15) * 4;

    float m = -1e30f;
    float2 ml[KSPLIT];
#pragma unroll
    for (int s = 0; s < KSPLIT; ++s) {
        ml[s] = MLp[(size_t)s * kB * kSQ + r];
        m = fmaxf(m, ml[s].x);
    }
    float acc[4] = {0.f, 0.f, 0.f, 0.f};
    float lsum = 0.f;
#pragma unroll
    for (int s = 0; s < KSPLIT; ++s) {
        const float wgt = __builtin_amdgcn_exp2f(ml[s].x - m) * ml[s].y;
        lsum += wgt;
        const f16x4 a = *(const f16x4*)&Ap[(size_t)s * APART + (size_t)r * kD + c];
#pragma unroll
        for (int j = 0; j < 4; ++j) acc[j] += wgt * (float)a[j];
    }
    const float inv = 1.0f / lsum;
    float4 res = make_float4(acc[0] * inv, acc[1] * inv, acc[2] * inv, acc[3] * inv);
    *(float4*)&Og[(size_t)r * kD + c] = res;
}

extern "C" void kernel_launch(void* const* d_in, const int* in_sizes, int n_in,
                              void* d_out, int out_size, void* d_ws, size_t ws_size,
                              hipStream_t stream) {
    const float* Q    = (const float*)d_in[0];
    const float* K    = (const float*)d_in[1];
    const float* V    = (const float*)d_in[2];
    const float* sdiv = (const float*)d_in[4];
    float* O = (float*)d_out;

    // workspace: Kh 4MB | Vt 4MB | Ap fp16 16.8MB | MLp 1MB
    _Float16* Kh  = (_Float16*)d_ws;
    _Float16* Vt  = Kh + (size_t)kB * kSK * kD;
    _Float16* Ap  = Vt + (size_t)kB * kSK * kD;
    float2*   MLp = (float2*)(Ap + (size_t)KSPLIT * APART);

    fattn_prepass<<<dim3(kSK / BK, kB), dim3(256), 0, stream>>>(K, V, Kh, Vt);
    fattn_partial<<<dim3((kSQ / BQ) * kB * KSPLIT), dim3(256), 0, stream>>>(Q, Kh, Vt, sdiv, Ap, MLp);
    fattn_combine<<<dim3(kB * kSQ * kD / (256 * 4)), dim3(256), 0, stream>>>(Ap, MLp, O);
}